// Round 1
// baseline (974.390 us; speedup 1.0000x reference)
//
#include <hip/hip_runtime.h>

#define NF 256
#define NC 64

// ---------------------------------------------------------------------------
// GCNConv: out[d] = b + dinv[d] * ( xws[d] + sum_{e: dst=d} xws[src_e] )
//          xws[n] = dinv[n] * (x @ W)[n],  dinv[n] = rsqrt(1 + indegree(n))
// ---------------------------------------------------------------------------

__global__ __launch_bounds__(256) void k_init_deg(float* __restrict__ deg, int n) {
    int i = blockIdx.x * blockDim.x + threadIdx.x;
    if (i < n) deg[i] = 1.0f;   // self-loop contributes 1
}

__global__ __launch_bounds__(256) void k_degree(const int* __restrict__ dst,
                                                float* __restrict__ deg, int ne) {
    int e = blockIdx.x * blockDim.x + threadIdx.x;
    if (e < ne) atomicAdd(&deg[dst[e]], 1.0f);
}

// One row per thread. 64 f32 accumulators in VGPRs. W is read at wave-uniform
// addresses (uniform loop counter) -> compiler should emit scalar s_load and
// broadcast via SGPR operand into v_fma_f32.
__global__ __launch_bounds__(256) void k_xw(const float* __restrict__ x,
                                            const float* __restrict__ W,
                                            const float* __restrict__ deg,
                                            float* __restrict__ xws,
                                            float* __restrict__ out, int n) {
    int r = blockIdx.x * blockDim.x + threadIdx.x;
    if (r >= n) return;
    float acc[NC];
#pragma unroll
    for (int c = 0; c < NC; ++c) acc[c] = 0.0f;

    const float4* xr = reinterpret_cast<const float4*>(x + (size_t)r * NF);
#pragma unroll 1
    for (int k4 = 0; k4 < NF / 4; ++k4) {
        float4 xv = xr[k4];
        const float* wk = W + (size_t)(k4 * 4) * NC;
        float xs0 = xv.x, xs1 = xv.y, xs2 = xv.z, xs3 = xv.w;
#pragma unroll
        for (int c = 0; c < NC; ++c) {
            float a = acc[c];
            a = fmaf(xs0, wk[0 * NC + c], a);
            a = fmaf(xs1, wk[1 * NC + c], a);
            a = fmaf(xs2, wk[2 * NC + c], a);
            a = fmaf(xs3, wk[3 * NC + c], a);
            acc[c] = a;
        }
    }
    float di = rsqrtf(deg[r]);
    float4* xo = reinterpret_cast<float4*>(xws + (size_t)r * NC);
    float4* oo = reinterpret_cast<float4*>(out + (size_t)r * NC);
#pragma unroll
    for (int c4 = 0; c4 < NC / 4; ++c4) {
        float4 v;
        v.x = acc[4 * c4 + 0] * di;
        v.y = acc[4 * c4 + 1] * di;
        v.z = acc[4 * c4 + 2] * di;
        v.w = acc[4 * c4 + 3] * di;
        xo[c4] = v;   // message values (gathered by scatter kernel)
        oo[c4] = v;   // self-loop term initializes the accumulator in d_out
    }
}

// 64 lanes per edge: lane c gathers xws[src][c] (256B contiguous per edge)
// and atomically accumulates into out[dst][c].
__global__ __launch_bounds__(256) void k_scatter(const int* __restrict__ src,
                                                 const int* __restrict__ dst,
                                                 const float* __restrict__ xws,
                                                 float* __restrict__ out, int ne) {
    int e = blockIdx.x * 4 + (threadIdx.x >> 6);
    if (e >= ne) return;
    int c = threadIdx.x & 63;
    int s = src[e];
    int d = dst[e];
    float v = xws[(size_t)s * NC + c];
    atomicAdd(&out[(size_t)d * NC + c], v);
}

__global__ __launch_bounds__(256) void k_final(const float* __restrict__ deg,
                                               const float* __restrict__ b,
                                               float* __restrict__ out, int n) {
    int i = blockIdx.x * blockDim.x + threadIdx.x;
    int total = n * NC;
    if (i >= total) return;
    int r = i >> 6;
    int c = i & 63;
    out[i] = out[i] * rsqrtf(deg[r]) + b[c];
}

extern "C" void kernel_launch(void* const* d_in, const int* in_sizes, int n_in,
                              void* d_out, int out_size, void* d_ws, size_t ws_size,
                              hipStream_t stream) {
    const float* x = (const float*)d_in[0];
    const float* W = (const float*)d_in[1];
    const float* b = (const float*)d_in[2];
    const int*   ei = (const int*)d_in[3];   // [2, NE]: row0 = src, row1 = dst
    float* out = (float*)d_out;

    int n  = in_sizes[0] / NF;
    int ne = in_sizes[3] / 2;
    const int* src = ei;
    const int* dst = ei + ne;

    // Workspace layout: deg [n floats] at offset 0, xws [n*64 floats] at +1MB.
    float* deg = (float*)d_ws;
    float* xws = (float*)((char*)d_ws + (1u << 20));

    k_init_deg<<<(n + 255) / 256, 256, 0, stream>>>(deg, n);
    k_degree<<<(ne + 255) / 256, 256, 0, stream>>>(dst, deg, ne);
    k_xw<<<(n + 255) / 256, 256, 0, stream>>>(x, W, deg, xws, out, n);
    k_scatter<<<(ne + 3) / 4, 256, 0, stream>>>(src, dst, xws, out, ne);
    k_final<<<(n * NC + 255) / 256, 256, 0, stream>>>(deg, b, out, n);
}

// Round 3
// 631.827 us; speedup vs baseline: 1.5422x; 1.5422x over previous
//
#include <hip/hip_runtime.h>

#define NF 256
#define NC 64
#define SCAN_CHUNK 1024   // elements per scan block (256 threads x 4)

// ---------------------------------------------------------------------------
// GCNConv: out[d] = b + dinv[d] * ( xws[d] + sum_{e: dst=d} xws[src_e] )
//          xws[n] = dinv[n] * (x @ W)[n],  dinv[n] = rsqrt(1 + indegree(n))
// Primary strategy: build CSR by destination (histogram + scan + fill), then
// a register-accumulating gather (no float atomics). Fallback (small ws):
// atomic-scatter path (verified in Round 1).
// ---------------------------------------------------------------------------

__global__ __launch_bounds__(256) void k_zero(int* __restrict__ p, int n) {
    int i = blockIdx.x * blockDim.x + threadIdx.x;
    if (i < n) p[i] = 0;
}

__global__ __launch_bounds__(256) void k_count(const int* __restrict__ dst,
                                               int* __restrict__ counts, int ne) {
    int e = blockIdx.x * blockDim.x + threadIdx.x;
    if (e < ne) atomicAdd(&counts[dst[e]], 1);
}

// Exclusive scan, stage 1: per-block partial exclusive scan + block sums.
__global__ __launch_bounds__(256) void k_scan1(const int* __restrict__ counts,
                                               int* __restrict__ excl,
                                               int* __restrict__ bsum, int n) {
    __shared__ int s[256];
    int t = threadIdx.x;
    int base = blockIdx.x * SCAN_CHUNK + t * 4;
    int v[4];
    int sum = 0;
#pragma unroll
    for (int k = 0; k < 4; ++k) {
        int idx = base + k;
        v[k] = (idx < n) ? counts[idx] : 0;
        sum += v[k];
    }
    s[t] = sum;
    __syncthreads();
#pragma unroll
    for (int off = 1; off < 256; off <<= 1) {
        int xv = (t >= off) ? s[t - off] : 0;
        __syncthreads();
        s[t] += xv;
        __syncthreads();
    }
    int excl_t = s[t] - sum;
    if (t == 255) bsum[blockIdx.x] = s[t];
    int run = excl_t;
#pragma unroll
    for (int k = 0; k < 4; ++k) {
        int idx = base + k;
        if (idx < n) { excl[idx] = run; run += v[k]; }
    }
}

// Stage 2: serial exclusive scan of the ~98 block sums (negligible).
__global__ void k_scan2(int* __restrict__ bsum, int nblk) {
    if (threadIdx.x == 0 && blockIdx.x == 0) {
        int run = 0;
        for (int i = 0; i < nblk; ++i) { int t = bsum[i]; bsum[i] = run; run += t; }
    }
}

// Stage 3: add block offsets -> rowptr (doubles as the fill cursor).
__global__ __launch_bounds__(256) void k_scan3(int* __restrict__ rowptr,
                                               const int* __restrict__ bsum, int n) {
    int i = blockIdx.x * blockDim.x + threadIdx.x;
    if (i < n) rowptr[i] += bsum[i / SCAN_CHUNK];
}

// Uses rowptr as the cursor: after this kernel rowptr[w] == end of row w.
__global__ __launch_bounds__(256) void k_fill(const int* __restrict__ src,
                                              const int* __restrict__ dst,
                                              int* __restrict__ rowptr,
                                              int* __restrict__ csr, int ne) {
    int e = blockIdx.x * blockDim.x + threadIdx.x;
    if (e < ne) {
        int pos = atomicAdd(&rowptr[dst[e]], 1);
        csr[pos] = src[e];
    }
}

// One row per thread; 64 f32 accumulators. W reads are wave-uniform -> s_load.
__global__ __launch_bounds__(256) void k_xw(const float* __restrict__ x,
                                            const float* __restrict__ W,
                                            const int* __restrict__ counts,
                                            float* __restrict__ xws, int n) {
    int r = blockIdx.x * blockDim.x + threadIdx.x;
    if (r >= n) return;
    float acc[NC];
#pragma unroll
    for (int c = 0; c < NC; ++c) acc[c] = 0.0f;

    const float4* xr = reinterpret_cast<const float4*>(x + (size_t)r * NF);
#pragma unroll 1
    for (int k4 = 0; k4 < NF / 4; ++k4) {
        float4 xv = xr[k4];
        const float* wk = W + (size_t)(k4 * 4) * NC;
#pragma unroll
        for (int c = 0; c < NC; ++c) {
            float a = acc[c];
            a = fmaf(xv.x, wk[0 * NC + c], a);
            a = fmaf(xv.y, wk[1 * NC + c], a);
            a = fmaf(xv.z, wk[2 * NC + c], a);
            a = fmaf(xv.w, wk[3 * NC + c], a);
            acc[c] = a;
        }
    }
    float di = rsqrtf((float)counts[r] + 1.0f);
    float4* xo = reinterpret_cast<float4*>(xws + (size_t)r * NC);
#pragma unroll
    for (int c4 = 0; c4 < NC / 4; ++c4) {
        float4 v;
        v.x = acc[4 * c4 + 0] * di;
        v.y = acc[4 * c4 + 1] * di;
        v.z = acc[4 * c4 + 2] * di;
        v.w = acc[4 * c4 + 3] * di;
        xo[c4] = v;
    }
}

// One wave per destination node; lane = output column. rowend = rowptr after
// fill (== row end); beg = rowend - counts[w].
__global__ __launch_bounds__(256) void k_gather(const int* __restrict__ rowend,
                                                const int* __restrict__ counts,
                                                const int* __restrict__ csr,
                                                const float* __restrict__ xws,
                                                const float* __restrict__ b,
                                                float* __restrict__ out, int n) {
    int w = (blockIdx.x * blockDim.x + threadIdx.x) >> 6;
    int lane = threadIdx.x & 63;
    if (w >= n) return;
    int cnt = counts[w];
    int end = rowend[w];
    int beg = end - cnt;

    float acc = xws[(size_t)w * NC + lane];   // self-loop term
    int j = beg;
    for (; j + 4 <= end; j += 4) {
        int s0 = csr[j + 0], s1 = csr[j + 1], s2 = csr[j + 2], s3 = csr[j + 3];
        float v0 = xws[(size_t)s0 * NC + lane];
        float v1 = xws[(size_t)s1 * NC + lane];
        float v2 = xws[(size_t)s2 * NC + lane];
        float v3 = xws[(size_t)s3 * NC + lane];
        acc += v0; acc += v1; acc += v2; acc += v3;
    }
    for (; j < end; ++j) acc += xws[(size_t)csr[j] * NC + lane];

    float di = rsqrtf((float)cnt + 1.0f);
    out[(size_t)w * NC + lane] = acc * di + b[lane];
}

// ---------------- Fallback path (Round 1, verified): atomic scatter ---------
__global__ __launch_bounds__(256) void k_init_deg(float* __restrict__ deg, int n) {
    int i = blockIdx.x * blockDim.x + threadIdx.x;
    if (i < n) deg[i] = 1.0f;
}
__global__ __launch_bounds__(256) void k_degree(const int* __restrict__ dst,
                                                float* __restrict__ deg, int ne) {
    int e = blockIdx.x * blockDim.x + threadIdx.x;
    if (e < ne) atomicAdd(&deg[dst[e]], 1.0f);
}
__global__ __launch_bounds__(256) void k_xw_fb(const float* __restrict__ x,
                                               const float* __restrict__ W,
                                               const float* __restrict__ deg,
                                               float* __restrict__ xws,
                                               float* __restrict__ out, int n) {
    int r = blockIdx.x * blockDim.x + threadIdx.x;
    if (r >= n) return;
    float acc[NC];
#pragma unroll
    for (int c = 0; c < NC; ++c) acc[c] = 0.0f;
    const float4* xr = reinterpret_cast<const float4*>(x + (size_t)r * NF);
#pragma unroll 1
    for (int k4 = 0; k4 < NF / 4; ++k4) {
        float4 xv = xr[k4];
        const float* wk = W + (size_t)(k4 * 4) * NC;
#pragma unroll
        for (int c = 0; c < NC; ++c) {
            float a = acc[c];
            a = fmaf(xv.x, wk[0 * NC + c], a);
            a = fmaf(xv.y, wk[1 * NC + c], a);
            a = fmaf(xv.z, wk[2 * NC + c], a);
            a = fmaf(xv.w, wk[3 * NC + c], a);
            acc[c] = a;
        }
    }
    float di = rsqrtf(deg[r]);
    float4* xo = reinterpret_cast<float4*>(xws + (size_t)r * NC);
    float4* oo = reinterpret_cast<float4*>(out + (size_t)r * NC);
#pragma unroll
    for (int c4 = 0; c4 < NC / 4; ++c4) {
        float4 v;
        v.x = acc[4 * c4 + 0] * di;
        v.y = acc[4 * c4 + 1] * di;
        v.z = acc[4 * c4 + 2] * di;
        v.w = acc[4 * c4 + 3] * di;
        xo[c4] = v;
        oo[c4] = v;
    }
}
__global__ __launch_bounds__(256) void k_scatter_fb(const int* __restrict__ src,
                                                    const int* __restrict__ dst,
                                                    const float* __restrict__ xws,
                                                    float* __restrict__ out, int ne) {
    int e = blockIdx.x * 4 + (threadIdx.x >> 6);
    if (e >= ne) return;
    int c = threadIdx.x & 63;
    float v = xws[(size_t)src[e] * NC + c];
    atomicAdd(&out[(size_t)dst[e] * NC + c], v);
}
__global__ __launch_bounds__(256) void k_final_fb(const float* __restrict__ deg,
                                                  const float* __restrict__ b,
                                                  float* __restrict__ out, int n) {
    int i = blockIdx.x * blockDim.x + threadIdx.x;
    if (i >= n * NC) return;
    out[i] = out[i] * rsqrtf(deg[i >> 6]) + b[i & 63];
}

extern "C" void kernel_launch(void* const* d_in, const int* in_sizes, int n_in,
                              void* d_out, int out_size, void* d_ws, size_t ws_size,
                              hipStream_t stream) {
    const float* x = (const float*)d_in[0];
    const float* W = (const float*)d_in[1];
    const float* b = (const float*)d_in[2];
    const int*   ei = (const int*)d_in[3];   // [2, NE]: row0 = src, row1 = dst
    float* out = (float*)d_out;

    int n  = in_sizes[0] / NF;
    int ne = in_sizes[3] / 2;
    const int* src = ei;
    const int* dst = ei + ne;

    // CSR-path workspace layout (bytes):
    //   counts @ 0           (n*4)
    //   rowptr @ cntB        (n*4)
    //   bsum   @ 2*cntB      (nblk*4)
    //   csr    @ csrOff      (ne*4)
    //   xws    @ xwsOff      (n*NC*4)
    size_t cntB   = (size_t)n * 4;
    size_t bsumB  = 4096;
    size_t csrOff = 2 * cntB + bsumB;
    size_t xwsOff = csrOff + (size_t)ne * 4;
    size_t needed = xwsOff + (size_t)n * NC * 4;

    if (ws_size >= needed) {
        char* wsb = (char*)d_ws;
        int*   counts = (int*)(wsb);
        int*   rowptr = (int*)(wsb + cntB);
        int*   bsum   = (int*)(wsb + 2 * cntB);
        int*   csr    = (int*)(wsb + csrOff);
        float* xws    = (float*)(wsb + xwsOff);
        int nblk = (n + SCAN_CHUNK - 1) / SCAN_CHUNK;

        k_zero  <<<(n + 255) / 256, 256, 0, stream>>>(counts, n);
        k_count <<<(ne + 255) / 256, 256, 0, stream>>>(dst, counts, ne);
        k_scan1 <<<nblk, 256, 0, stream>>>(counts, rowptr, bsum, n);
        k_scan2 <<<1, 64, 0, stream>>>(bsum, nblk);
        k_scan3 <<<(n + 255) / 256, 256, 0, stream>>>(rowptr, bsum, n);
        k_xw    <<<(n + 255) / 256, 256, 0, stream>>>(x, W, counts, xws, n);
        k_fill  <<<(ne + 255) / 256, 256, 0, stream>>>(src, dst, rowptr, csr, ne);
        // one wave (64 threads) per node:
        k_gather<<<((size_t)n * 64 + 255) / 256, 256, 0, stream>>>(rowptr, counts, csr, xws, b, out, n);
    } else {
        // Fallback: verified Round-1 atomic-scatter path (~26.6MB ws).
        float* deg = (float*)d_ws;
        float* xws = (float*)((char*)d_ws + (1u << 20));
        k_init_deg<<<(n + 255) / 256, 256, 0, stream>>>(deg, n);
        k_degree  <<<(ne + 255) / 256, 256, 0, stream>>>(dst, deg, ne);
        k_xw_fb   <<<(n + 255) / 256, 256, 0, stream>>>(x, W, deg, xws, out, n);
        k_scatter_fb<<<(ne + 3) / 4, 256, 0, stream>>>(src, dst, xws, out, ne);
        k_final_fb<<<(n * NC + 255) / 256, 256, 0, stream>>>(deg, b, out, n);
    }
}